// Round 5
// baseline (6118.380 us; speedup 1.0000x reference)
//
#include <hip/hip_runtime.h>
#include <hip/hip_bf16.h>
#include <hip/hip_cooperative_groups.h>

namespace cg = cooperative_groups;

// ============================================================================
// PreferenceConditionedDecoder on MI355X — R5
//   prep_misc : X->bf16, weight repacks (bf16), h0/c0 init
//   prep_pref : pref = LN(relu(preference @ pref_W + pref_b))
//   gemm_kv   : bf16 MFMA GEMM, XCD swizzle, fp8 K/V out
//   loop_k    : persistent cooperative; attention streams K/V via
//               global_load_lds (16B) double-buffered tiles; gates bf16+padded
//   epilogue_k: all logits at once
// ============================================================================

typedef __bf16 bf16;
typedef __attribute__((ext_vector_type(8))) __bf16 bf16x8;
typedef __attribute__((ext_vector_type(4))) __bf16 bf16x4;
typedef __attribute__((ext_vector_type(4))) float f32x4;
typedef __attribute__((ext_vector_type(2))) float f32x2;

#define B_  32
#define T_  2048
#define H_  256
#define S_  32

static __device__ __forceinline__ float sigmoidf_(float x){ return 1.f/(1.f+__expf(-x)); }
static __device__ __forceinline__ float tanhf_(float x){ float e=__expf(2.f*x); return (e-1.f)/(e+1.f); }

static __device__ __forceinline__ void async_cp16(void* lds, const void* g){
  __builtin_amdgcn_global_load_lds(
      (const __attribute__((address_space(1))) unsigned int*)g,
      (__attribute__((address_space(3))) unsigned int*)lds, 16, 0, 0);
}

// ---------------------------------------------------------------- prep_misc
#define NX4_ 8388608   // 32*2048*512/4
__global__ void prep_misc(const float* __restrict__ X,
                          const float* __restrict__ Wq, const float* __restrict__ Wk,
                          const float* __restrict__ Wv, const float* __restrict__ Wo,
                          const float* __restrict__ Wih, const float* __restrict__ Whh,
                          const float* __restrict__ context,
                          bf16* __restrict__ Xb,
                          bf16* __restrict__ WkvT, bf16* __restrict__ WqB, bf16* __restrict__ WoT,
                          bf16* __restrict__ WihB, bf16* __restrict__ WhhB,
                          float* __restrict__ h0, float* __restrict__ c0)
{
  const int total = NX4_ + 524288+262144+131072+786432+262144+8192+8192;
  for (int i = blockIdx.x*blockDim.x + threadIdx.x; i < total; i += gridDim.x*blockDim.x){
    if (i < NX4_){
      float4 x4 = *(const float4*)&X[(size_t)i*4];
      bf16x4 o; o[0]=(bf16)x4.x; o[1]=(bf16)x4.y; o[2]=(bf16)x4.z; o[3]=(bf16)x4.w;
      *(bf16x4*)&Xb[(size_t)i*4] = o;
      continue;
    }
    int x = i - NX4_;
    if (x < 524288){ int n = x>>9, k = x&511;              // WkvT[n][k] = [Wk|Wv][k][n]
      WkvT[x] = (bf16)(n<512 ? Wk[k*512+n] : Wv[k*512+(n-512)]); continue; }
    x -= 524288;
    if (x < 262144){ WqB[x] = (bf16)Wq[x]; continue; }      // plain bf16 copy [k][n]
    x -= 262144;
    if (x < 131072){ int h = x>>14, rem = x&16383, j = rem>>6, d = rem&63;  // WoT[h][j][d]
      WoT[x] = (bf16)Wo[(h*64+d)*512 + j]; continue; }
    x -= 131072;
    if (x < 786432){ WihB[x] = (bf16)Wih[x]; continue; }
    x -= 786432;
    if (x < 262144){ WhhB[x] = (bf16)Whh[x]; continue; }
    x -= 262144;
    if (x < 8192){ h0[x] = context[x]; continue; }          // h0 = context (B,H)
    x -= 8192;
    c0[x] = 0.f;
  }
}

// ---------------------------------------------------------------- prep_pref
__global__ __launch_bounds__(256) void prep_pref(const float* __restrict__ preference,
                                                 const float* __restrict__ pref_W,
                                                 const float* __restrict__ pref_b,
                                                 const float* __restrict__ ln_g,
                                                 const float* __restrict__ ln_b,
                                                 float* __restrict__ prefb)
{
  __shared__ float red_[4];
  int b = blockIdx.x, j = threadIdx.x;
  float p0 = preference[b*2], p1 = preference[b*2+1];
  float v = fmaxf(p0*pref_W[j] + p1*pref_W[256+j] + pref_b[j], 0.f);
  float s = v;
  #pragma unroll
  for (int o=32;o;o>>=1) s += __shfl_xor(s,o);
  if ((j&63)==0) red_[j>>6] = s;
  __syncthreads();
  float mean = (red_[0]+red_[1]+red_[2]+red_[3]) * (1.f/256.f);
  __syncthreads();
  float d = v - mean;
  float s2 = d*d;
  #pragma unroll
  for (int o=32;o;o>>=1) s2 += __shfl_xor(s2,o);
  if ((j&63)==0) red_[j>>6] = s2;
  __syncthreads();
  float var = (red_[0]+red_[1]+red_[2]+red_[3]) * (1.f/256.f);
  prefb[b*256+j] = d * rsqrtf(var + 1e-5f) * ln_g[j] + ln_b[j];
}

// ---------------------------------------------------------------- gemm_kv
__global__ __launch_bounds__(256) void gemm_kv(const bf16* __restrict__ Xb,
                                               const bf16* __restrict__ WkvT,
                                               const float* __restrict__ bk, const float* __restrict__ bv,
                                               unsigned char* __restrict__ Kf8, unsigned char* __restrict__ Vf8)
{
  __shared__ __align__(16) bf16 As[128*40];
  __shared__ __align__(16) bf16 Bs[128*40];
  int blk = blockIdx.x;
  int bm = ((blk>>6)<<3) | (blk&7);
  int bn = (blk>>3)&7;
  int m0 = bm<<7, n0 = bn<<7;
  int tid = threadIdx.x;
  int lane = tid&63, wave = tid>>6;
  int wm = (wave>>1)<<6, wn = (wave&1)<<6;
  int q = lane>>4, li = lane&15;
  int r0 = tid>>2, oct = tid&3;
  const bf16* A0 = &Xb[(size_t)(m0+r0)*512 + oct*8];
  const bf16* A1 = A0 + (size_t)64*512;
  const bf16* B0 = &WkvT[(size_t)(n0+r0)*512 + oct*8];
  const bf16* B1 = B0 + (size_t)64*512;
  f32x4 acc[4][4];
  #pragma unroll
  for (int a=0;a<4;a++)
    #pragma unroll
    for (int b=0;b<4;b++) acc[a][b] = (f32x4){0.f,0.f,0.f,0.f};

  bf16x8 apf0 = *(const bf16x8*)A0, apf1 = *(const bf16x8*)A1;
  bf16x8 bpf0 = *(const bf16x8*)B0, bpf1 = *(const bf16x8*)B1;

  for (int k0=0;k0<512;k0+=32){
    __syncthreads();
    *(bf16x8*)&As[r0*40+oct*8]      = apf0;
    *(bf16x8*)&As[(r0+64)*40+oct*8] = apf1;
    *(bf16x8*)&Bs[r0*40+oct*8]      = bpf0;
    *(bf16x8*)&Bs[(r0+64)*40+oct*8] = bpf1;
    __syncthreads();
    if (k0+32 < 512){
      apf0 = *(const bf16x8*)(A0 + k0+32);
      apf1 = *(const bf16x8*)(A1 + k0+32);
      bpf0 = *(const bf16x8*)(B0 + k0+32);
      bpf1 = *(const bf16x8*)(B1 + k0+32);
    }
    bf16x8 af[4], bfr[4];
    #pragma unroll
    for (int mt=0;mt<4;mt++) af[mt] = *(const bf16x8*)&As[(wm+mt*16+li)*40 + q*8];
    #pragma unroll
    for (int nt=0;nt<4;nt++) bfr[nt] = *(const bf16x8*)&Bs[(wn+nt*16+li)*40 + q*8];
    #pragma unroll
    for (int mt=0;mt<4;mt++)
      #pragma unroll
      for (int nt=0;nt<4;nt++)
        acc[mt][nt] = __builtin_amdgcn_mfma_f32_16x16x32_bf16(bfr[nt], af[mt], acc[mt][nt], 0,0,0);
  }
  #pragma unroll
  for (int mt=0;mt<4;mt++){
    int mm = m0 + wm + mt*16 + li;
    int b = mm>>11, t = mm&2047;
    #pragma unroll
    for (int nt=0;nt<4;nt++){
      int nb = n0 + wn + nt*16 + q*4;
      const float* bias = (nb<512) ? (bk+nb) : (bv+nb-512);
      unsigned char* dst = (nb<512) ? Kf8 : Vf8;
      int nn = nb & 511;
      int h = nn>>6, d0 = nn&63;
      unsigned int p = 0;
      p = __builtin_amdgcn_cvt_pk_fp8_f32(acc[mt][nt][0]+bias[0], acc[mt][nt][1]+bias[1], p, false);
      p = __builtin_amdgcn_cvt_pk_fp8_f32(acc[mt][nt][2]+bias[2], acc[mt][nt][3]+bias[3], p, true);
      *(unsigned int*)&dst[(((size_t)(b*8+h))*T_ + (size_t)t)*64 + d0] = p;
    }
  }
}

// ---------------------------------------------------------------- loop_k
// 256 blocks x 1024 threads, 1 block/CU. Phase A: (b,h) attention, K/V tiles
// (128 rows = 8KB K + 8KB V) staged via global_load_lds, double-buffered.
// Phase C: (b, jblk) gates with bf16 weights, padded LDS, fused LSTM.
__global__ __launch_bounds__(1024, 4) void loop_k(
    const unsigned char* __restrict__ Kf8, const unsigned char* __restrict__ Vf8,
    const bf16* __restrict__ WqB, const bf16* __restrict__ WoT,
    const float* __restrict__ bq, const float* __restrict__ prefb,
    const bf16* __restrict__ WihB, const bf16* __restrict__ WhhB,
    const float* __restrict__ b_ih, const float* __restrict__ b_hh,
    const float* __restrict__ bo,
    float* __restrict__ h_hist, float* __restrict__ c_cur,
    float* __restrict__ ctx_part, float* __restrict__ ctx_hist)
{
  cg::grid_group grid = cg::this_grid();
  __shared__ __align__(16) unsigned char KVs[2][16384];   // [buf][K 8KB | V 8KB]
  __shared__ float q_s[512];
  __shared__ float qh_s[64];
  __shared__ float aw[16][64];
  __shared__ float zw[16];
  __shared__ float attn_s[64];
  __shared__ float xh_s[8*132];
  __shared__ float gv_s[128];
  const int tid = threadIdx.x;
  const int b = blockIdx.x>>3, sub = blockIdx.x&7;
  const int h = sub;
  const int lane = tid&63, wave = tid>>6;
  const int ro = lane>>3, dq = lane&7;     // 8 rows x 8 d-octets per wave-pass
  const unsigned char* Kb = Kf8 + ((size_t)(b*8+h))*T_*64;
  const unsigned char* Vb = Vf8 + ((size_t)(b*8+h))*T_*64;

  for (int s=0; s<S_; ++s){
    const float* h_cur = h_hist + (size_t)s*8192;
    // issue tile 0 async (flies during q/qh setup)
    if (wave < 8) async_cp16(&KVs[0][wave*1024],            Kb + wave*1024 + lane*16);
    else          async_cp16(&KVs[0][8192 + (wave-8)*1024], Vb + (wave-8)*1024 + lane*16);
    if (tid < 512) q_s[tid] = (tid<256) ? h_cur[b*256+tid] : prefb[b*256+(tid-256)];
    __syncthreads();
    // qh partials: wave w covers k in [w*32,w*32+32); lane = d. q_s broadcast,
    // WqB coalesced (128B/row). aw reused as partial buffer.
    { float sd = 0.f;
      const bf16* wq = &WqB[(size_t)(wave*32)*512 + h*64 + lane];
      #pragma unroll 8
      for (int i=0;i<32;i++) sd += q_s[wave*32+i]*(float)wq[(size_t)i*512];
      aw[wave][lane] = sd;
    }
    __syncthreads();
    if (tid < 64){
      float sd = 0.f;
      #pragma unroll
      for (int w=0;w<16;w++) sd += aw[w][tid];
      qh_s[tid] = (sd + bq[h*64+tid])*0.125f;
    }
    __syncthreads();
    f32x2 qh2[4];
    #pragma unroll
    for (int j=0;j<4;j++){ qh2[j].x = qh_s[dq*8+j*2]; qh2[j].y = qh_s[dq*8+j*2+1]; }
    float z = 0.f;
    f32x2 acc2[4];
    #pragma unroll
    for (int j=0;j<4;j++) acc2[j] = (f32x2){0.f,0.f};
    // ---- K/V tile loop: 16 tiles x 128 rows, dbuf via global_load_lds
    for (int tile=0; tile<16; ++tile){
      __syncthreads();                       // tile's staged data ready
      if (tile < 15){
        unsigned char* bufn = KVs[(tile+1)&1];
        const unsigned char* Kn = Kb + (tile+1)*8192;
        const unsigned char* Vn = Vb + (tile+1)*8192;
        if (wave < 8) async_cp16(bufn + wave*1024,            Kn + wave*1024 + lane*16);
        else          async_cp16(bufn + 8192 + (wave-8)*1024, Vn + (wave-8)*1024 + lane*16);
      }
      const unsigned char* Kt = KVs[tile&1];
      int off = (wave*8 + ro)*64 + dq*8;
      uint2 k2 = *(const uint2*)&Kt[off];
      uint2 v2 = *(const uint2*)&Kt[8192 + off];
      f32x2 s2;
      s2  = qh2[0]*__builtin_amdgcn_cvt_pk_f32_fp8(k2.x,false);
      s2 += qh2[1]*__builtin_amdgcn_cvt_pk_f32_fp8(k2.x,true);
      s2 += qh2[2]*__builtin_amdgcn_cvt_pk_f32_fp8(k2.y,false);
      s2 += qh2[3]*__builtin_amdgcn_cvt_pk_f32_fp8(k2.y,true);
      float sc = s2.x + s2.y;
      sc += __shfl_xor(sc,1); sc += __shfl_xor(sc,2); sc += __shfl_xor(sc,4);
      float e = __expf(fminf(sc, 80.f));
      z += e;
      f32x2 e2 = (f32x2){e,e};
      acc2[0] += e2*__builtin_amdgcn_cvt_pk_f32_fp8(v2.x,false);
      acc2[1] += e2*__builtin_amdgcn_cvt_pk_f32_fp8(v2.x,true);
      acc2[2] += e2*__builtin_amdgcn_cvt_pk_f32_fp8(v2.y,false);
      acc2[3] += e2*__builtin_amdgcn_cvt_pk_f32_fp8(v2.y,true);
    }
    // reduce over rows (ro): strides 8,16,32 keep dq intact
    #pragma unroll
    for (int j=0;j<4;j++){
      acc2[j].x += __shfl_xor(acc2[j].x,8);  acc2[j].y += __shfl_xor(acc2[j].y,8);
      acc2[j].x += __shfl_xor(acc2[j].x,16); acc2[j].y += __shfl_xor(acc2[j].y,16);
      acc2[j].x += __shfl_xor(acc2[j].x,32); acc2[j].y += __shfl_xor(acc2[j].y,32);
    }
    z += __shfl_xor(z,8); z += __shfl_xor(z,16); z += __shfl_xor(z,32);
    if (ro==0){
      #pragma unroll
      for (int j=0;j<4;j++){ aw[wave][dq*8+j*2] = acc2[j].x; aw[wave][dq*8+j*2+1] = acc2[j].y; }
      if (dq==0) zw[wave] = z;
    }
    __syncthreads();
    if (tid < 64){
      float Z = 0.f, a = 0.f;
      #pragma unroll
      for (int w=0;w<16;w++){ Z += zw[w]; a += aw[w][tid]; }
      attn_s[tid] = a / Z;
    }
    __syncthreads();
    { // ctx_part[(b,h), j] = attn . Wo[h*64:(h+1)*64, j]
      int j = tid>>2, p4 = tid&3;
      const bf16* wo = &WoT[(((size_t)h*256)+j)*64 + p4*16];
      const float* at = &attn_s[p4*16];
      float cp = 0.f;
      #pragma unroll
      for (int i=0;i<2;i++){
        bf16x8 w8 = *(const bf16x8*)&wo[i*8];
        #pragma unroll
        for (int u=0;u<8;u++) cp += at[i*8+u]*(float)w8[u];
      }
      cp += __shfl_xor(cp,1); cp += __shfl_xor(cp,2);
      if (p4==0) ctx_part[(size_t)(b*8+h)*256 + j] = cp;
    }
    grid.sync();
    // ---------------- phase C: gates for (b, jblk=sub), bf16 weights
    { int k = tid; float xv;
      if (k < 256) xv = q_s[k];
      else if (k < 512){
        int j2 = k-256;
        float c8 = bo[j2];
        #pragma unroll
        for (int h2=0;h2<8;h2++) c8 += ctx_part[(size_t)(b*8+h2)*256 + j2];
        xv = c8;
        if (sub==0) ctx_hist[(size_t)s*8192 + b*256 + j2] = c8;
      }
      else if (k < 768) xv = q_s[k-256];   // pref
      else xv = q_s[k-768];                // h again
      xh_s[(k>>7)*132 + (k&127)] = xv;     // padded: stride 132 per 128-chunk
    }
    __syncthreads();
    { int n4 = tid>>3, p = tid&7;
      int g = n4>>5, j = sub*32 + (n4&31);
      int n = g*256 + j;
      const bf16* w; const float* x;
      if (p < 6){ w = &WihB[(size_t)n*768 + p*128]; x = &xh_s[p*132]; }
      else      { w = &WhhB[(size_t)n*256 + (p-6)*128]; x = &xh_s[p*132]; }
      float sum = 0.f;
      #pragma unroll
      for (int i=0;i<16;i++){
        bf16x8 w8 = *(const bf16x8*)&w[i*8];
        const float* xx = &x[i*8];
        #pragma unroll
        for (int u=0;u<8;u++) sum += (float)w8[u]*xx[u];
      }
      sum += __shfl_xor(sum,1); sum += __shfl_xor(sum,2); sum += __shfl_xor(sum,4);
      if (p==0) gv_s[n4] = sum + b_ih[n] + b_hh[n];
    }
    __syncthreads();
    if (tid < 32){
      int j = sub*32 + tid;
      float iv = gv_s[tid], fv = gv_s[32+tid], gg = gv_s[64+tid], ov = gv_s[96+tid];
      float cp = c_cur[b*256+j];
      float cn = sigmoidf_(fv)*cp + sigmoidf_(iv)*tanhf_(gg);
      float hn = sigmoidf_(ov)*tanhf_(cn);
      c_cur[b*256+j] = cn;
      h_hist[(size_t)(s+1)*8192 + b*256 + j] = hn;
    }
    grid.sync();
  }
}

// ---------------------------------------------------------------- epilogue
__global__ __launch_bounds__(256) void epilogue_k(const float* __restrict__ h_hist, const float* __restrict__ ctx_hist,
                                                  const float* __restrict__ prefb, const float* __restrict__ hW1,
                                                  const float* __restrict__ hb1, const float* __restrict__ hW2,
                                                  const float* __restrict__ hb2, float* __restrict__ out)
{
  __shared__ float dec[8][768];
  __shared__ float hid[8][260];
  int blk = blockIdx.x;
  int tid = threadIdx.x;
  #pragma unroll
  for (int i=0;i<8;i++){
    int sb = blk*8+i;
    int s = sb>>5, b = sb&31;
    for (int k=tid; k<768; k+=256){
      float v;
      if (k<256)      v = h_hist[((size_t)(s+1)*32 + b)*256 + k];
      else if (k<512) v = ctx_hist[((size_t)s*32 + b)*256 + (k-256)];
      else            v = prefb[b*256 + (k-512)];
      dec[i][k] = v;
    }
  }
  __syncthreads();
  float a[8];
  #pragma unroll
  for (int i=0;i<8;i++) a[i]=0.f;
  for (int k=0;k<768;k++){
    float w = hW1[(size_t)k*256 + tid];
    #pragma unroll
    for (int i=0;i<8;i++) a[i] += dec[i][k]*w;
  }
  float b1 = hb1[tid];
  #pragma unroll
  for (int i=0;i<8;i++) hid[i][tid] = fmaxf(a[i]+b1, 0.f);
  __syncthreads();
  if (tid < 128){
    int i = tid>>4, r = tid&15;
    float s2 = 0.f;
    for (int j2=0;j2<256;j2++) s2 += hid[i][j2]*hW2[j2*16+r];
    s2 += hb2[r];
    int sb = blk*8+i;
    int st = sb>>5, b = sb&31;
    out[(size_t)b*512 + st*16 + r] = s2;
  }
}

// ---------------------------------------------------------------- launch
extern "C" void kernel_launch(void* const* d_in, const int* in_sizes, int n_in,
                              void* d_out, int out_size, void* d_ws, size_t ws_size,
                              hipStream_t stream)
{
  const float* X          = (const float*)d_in[0];
  const float* context    = (const float*)d_in[1];
  const float* preference = (const float*)d_in[2];
  const float* pref_W     = (const float*)d_in[3];
  const float* pref_b     = (const float*)d_in[4];
  const float* ln_g       = (const float*)d_in[5];
  const float* ln_b       = (const float*)d_in[6];
  const float* Wq         = (const float*)d_in[7];
  const float* bq         = (const float*)d_in[8];
  const float* Wk         = (const float*)d_in[9];
  const float* bk         = (const float*)d_in[10];
  const float* Wv         = (const float*)d_in[11];
  const float* bv         = (const float*)d_in[12];
  const float* Wo         = (const float*)d_in[13];
  const float* bo         = (const float*)d_in[14];
  const float* W_ih       = (const float*)d_in[15];
  const float* b_ih       = (const float*)d_in[16];
  const float* W_hh       = (const float*)d_in[17];
  const float* b_hh       = (const float*)d_in[18];
  const float* hW1        = (const float*)d_in[19];
  const float* hb1        = (const float*)d_in[20];
  const float* hW2        = (const float*)d_in[21];
  const float* hb2        = (const float*)d_in[22];
  float* out = (float*)d_out;

  char* ws = (char*)d_ws;
  size_t off = 0;
  auto alloc = [&](size_t bytes)->char*{ char* p = ws+off; off += (bytes+255)&~(size_t)255; return p; };
  bf16* Xb           = (bf16*)alloc((size_t)B_*T_*512*2);            // 67 MB
  unsigned char* Kf8 = (unsigned char*)alloc((size_t)B_*8*T_*64);    // 33.5 MB
  unsigned char* Vf8 = (unsigned char*)alloc((size_t)B_*8*T_*64);    // 33.5 MB
  bf16* WkvT     = (bf16*)alloc(1024ull*512*2);
  bf16* WqB      = (bf16*)alloc(512ull*512*2);
  bf16* WoT      = (bf16*)alloc(8ull*256*64*2);
  bf16* WihB     = (bf16*)alloc(1024ull*768*2);
  bf16* WhhB     = (bf16*)alloc(1024ull*256*2);
  float* prefb   = (float*)alloc(8192ull*4);
  float* h_hist  = (float*)alloc(33ull*8192*4);
  float* c_cur   = (float*)alloc(8192ull*4);
  float* ctx_part= (float*)alloc(256ull*256*4);
  float* ctx_hist= (float*)alloc(32ull*8192*4);
  (void)ws_size; (void)in_sizes; (void)n_in; (void)out_size;

  hipLaunchKernelGGL(prep_misc, dim3(2048), dim3(256), 0, stream,
                     X, Wq,Wk,Wv,Wo,W_ih,W_hh, context,
                     Xb, WkvT,WqB,WoT,WihB,WhhB, h_hist, c_cur);
  hipLaunchKernelGGL(prep_pref, dim3(32), dim3(256), 0, stream,
                     preference, pref_W, pref_b, ln_g, ln_b, prefb);
  hipLaunchKernelGGL(gemm_kv, dim3(4096), dim3(256), 0, stream, Xb, WkvT, bk, bv, Kf8, Vf8);
  {
    void* args[] = { (void*)&Kf8, (void*)&Vf8, (void*)&WqB, (void*)&WoT,
                     (void*)&bq, (void*)&prefb, (void*)&WihB, (void*)&WhhB,
                     (void*)&b_ih, (void*)&b_hh, (void*)&bo,
                     (void*)&h_hist, (void*)&c_cur, (void*)&ctx_part, (void*)&ctx_hist };
    hipLaunchCooperativeKernel((const void*)loop_k, dim3(256), dim3(1024), args, 0, stream);
  }
  hipLaunchKernelGGL(epilogue_k, dim3(128), dim3(256), 0, stream,
                     h_hist, ctx_hist, prefb, hW1, hb1, hW2, hb2, out);
}

// Round 6
// 1509.684 us; speedup vs baseline: 4.0528x; 4.0528x over previous
//
#include <hip/hip_runtime.h>
#include <hip/hip_bf16.h>

// ============================================================================
// PreferenceConditionedDecoder on MI355X — R6
//   prep_misc : X->bf16, weight repacks (bf16), h0/c0 init
//   prep_pref : pref = LN(relu(preference @ pref_W + pref_b))
//   gemm_kv   : bf16 MFMA GEMM, XCD swizzle, fp8 K/V out
//   32x { attn_step (256 blk x 1024 thr, reg-pipelined fp8 K/V stream,
//                    plain ctx_part stores),
//         gates_step (256 blk, bf16 weights, fused LSTM + ctx reduce) }
//   epilogue_k: all logits at once
// NOTE: cooperative/persistent variant (R4/R5) regressed 3x — grid.sync()
// L2-invalidation + convergence cost ~180us/step. Per-step kernels win.
// ============================================================================

typedef __bf16 bf16;
typedef __attribute__((ext_vector_type(8))) __bf16 bf16x8;
typedef __attribute__((ext_vector_type(4))) __bf16 bf16x4;
typedef __attribute__((ext_vector_type(4))) float f32x4;
typedef __attribute__((ext_vector_type(2))) float f32x2;

#define B_  32
#define T_  2048
#define H_  256
#define S_  32

static __device__ __forceinline__ float sigmoidf_(float x){ return 1.f/(1.f+__expf(-x)); }
static __device__ __forceinline__ float tanhf_(float x){ float e=__expf(2.f*x); return (e-1.f)/(e+1.f); }

// ---------------------------------------------------------------- prep_misc
#define NX4_ 8388608   // 32*2048*512/4
__global__ void prep_misc(const float* __restrict__ X,
                          const float* __restrict__ Wq, const float* __restrict__ Wk,
                          const float* __restrict__ Wv, const float* __restrict__ Wo,
                          const float* __restrict__ Wih, const float* __restrict__ Whh,
                          const float* __restrict__ context,
                          bf16* __restrict__ Xb,
                          bf16* __restrict__ WkvT, bf16* __restrict__ WqB, bf16* __restrict__ WoT,
                          bf16* __restrict__ WihB, bf16* __restrict__ WhhB,
                          float* __restrict__ h0, float* __restrict__ c0)
{
  const int total = NX4_ + 524288+262144+131072+786432+262144+8192+8192;
  for (int i = blockIdx.x*blockDim.x + threadIdx.x; i < total; i += gridDim.x*blockDim.x){
    if (i < NX4_){
      float4 x4 = *(const float4*)&X[(size_t)i*4];
      bf16x4 o; o[0]=(bf16)x4.x; o[1]=(bf16)x4.y; o[2]=(bf16)x4.z; o[3]=(bf16)x4.w;
      *(bf16x4*)&Xb[(size_t)i*4] = o;
      continue;
    }
    int x = i - NX4_;
    if (x < 524288){ int n = x>>9, k = x&511;              // WkvT[n][k] = [Wk|Wv][k][n]
      WkvT[x] = (bf16)(n<512 ? Wk[k*512+n] : Wv[k*512+(n-512)]); continue; }
    x -= 524288;
    if (x < 262144){ WqB[x] = (bf16)Wq[x]; continue; }      // plain bf16 copy [k][n]
    x -= 262144;
    if (x < 131072){ int h = x>>14, rem = x&16383, j = rem>>6, d = rem&63;  // WoT[h][j][d]
      WoT[x] = (bf16)Wo[(h*64+d)*512 + j]; continue; }
    x -= 131072;
    if (x < 786432){ WihB[x] = (bf16)Wih[x]; continue; }
    x -= 786432;
    if (x < 262144){ WhhB[x] = (bf16)Whh[x]; continue; }
    x -= 262144;
    if (x < 8192){ h0[x] = context[x]; continue; }          // h0 = context (B,H)
    x -= 8192;
    c0[x] = 0.f;
  }
}

// ---------------------------------------------------------------- prep_pref
__global__ __launch_bounds__(256) void prep_pref(const float* __restrict__ preference,
                                                 const float* __restrict__ pref_W,
                                                 const float* __restrict__ pref_b,
                                                 const float* __restrict__ ln_g,
                                                 const float* __restrict__ ln_b,
                                                 float* __restrict__ prefb)
{
  __shared__ float red_[4];
  int b = blockIdx.x, j = threadIdx.x;
  float p0 = preference[b*2], p1 = preference[b*2+1];
  float v = fmaxf(p0*pref_W[j] + p1*pref_W[256+j] + pref_b[j], 0.f);
  float s = v;
  #pragma unroll
  for (int o=32;o;o>>=1) s += __shfl_xor(s,o);
  if ((j&63)==0) red_[j>>6] = s;
  __syncthreads();
  float mean = (red_[0]+red_[1]+red_[2]+red_[3]) * (1.f/256.f);
  __syncthreads();
  float d = v - mean;
  float s2 = d*d;
  #pragma unroll
  for (int o=32;o;o>>=1) s2 += __shfl_xor(s2,o);
  if ((j&63)==0) red_[j>>6] = s2;
  __syncthreads();
  float var = (red_[0]+red_[1]+red_[2]+red_[3]) * (1.f/256.f);
  prefb[b*256+j] = d * rsqrtf(var + 1e-5f) * ln_g[j] + ln_b[j];
}

// ---------------------------------------------------------------- gemm_kv
__global__ __launch_bounds__(256) void gemm_kv(const bf16* __restrict__ Xb,
                                               const bf16* __restrict__ WkvT,
                                               const float* __restrict__ bk, const float* __restrict__ bv,
                                               unsigned char* __restrict__ Kf8, unsigned char* __restrict__ Vf8)
{
  __shared__ __align__(16) bf16 As[128*40];
  __shared__ __align__(16) bf16 Bs[128*40];
  int blk = blockIdx.x;
  int bm = ((blk>>6)<<3) | (blk&7);
  int bn = (blk>>3)&7;
  int m0 = bm<<7, n0 = bn<<7;
  int tid = threadIdx.x;
  int lane = tid&63, wave = tid>>6;
  int wm = (wave>>1)<<6, wn = (wave&1)<<6;
  int q = lane>>4, li = lane&15;
  int r0 = tid>>2, oct = tid&3;
  const bf16* A0 = &Xb[(size_t)(m0+r0)*512 + oct*8];
  const bf16* A1 = A0 + (size_t)64*512;
  const bf16* B0 = &WkvT[(size_t)(n0+r0)*512 + oct*8];
  const bf16* B1 = B0 + (size_t)64*512;
  f32x4 acc[4][4];
  #pragma unroll
  for (int a=0;a<4;a++)
    #pragma unroll
    for (int b=0;b<4;b++) acc[a][b] = (f32x4){0.f,0.f,0.f,0.f};

  bf16x8 apf0 = *(const bf16x8*)A0, apf1 = *(const bf16x8*)A1;
  bf16x8 bpf0 = *(const bf16x8*)B0, bpf1 = *(const bf16x8*)B1;

  for (int k0=0;k0<512;k0+=32){
    __syncthreads();
    *(bf16x8*)&As[r0*40+oct*8]      = apf0;
    *(bf16x8*)&As[(r0+64)*40+oct*8] = apf1;
    *(bf16x8*)&Bs[r0*40+oct*8]      = bpf0;
    *(bf16x8*)&Bs[(r0+64)*40+oct*8] = bpf1;
    __syncthreads();
    if (k0+32 < 512){
      apf0 = *(const bf16x8*)(A0 + k0+32);
      apf1 = *(const bf16x8*)(A1 + k0+32);
      bpf0 = *(const bf16x8*)(B0 + k0+32);
      bpf1 = *(const bf16x8*)(B1 + k0+32);
    }
    bf16x8 af[4], bfr[4];
    #pragma unroll
    for (int mt=0;mt<4;mt++) af[mt] = *(const bf16x8*)&As[(wm+mt*16+li)*40 + q*8];
    #pragma unroll
    for (int nt=0;nt<4;nt++) bfr[nt] = *(const bf16x8*)&Bs[(wn+nt*16+li)*40 + q*8];
    #pragma unroll
    for (int mt=0;mt<4;mt++)
      #pragma unroll
      for (int nt=0;nt<4;nt++)
        acc[mt][nt] = __builtin_amdgcn_mfma_f32_16x16x32_bf16(bfr[nt], af[mt], acc[mt][nt], 0,0,0);
  }
  #pragma unroll
  for (int mt=0;mt<4;mt++){
    int mm = m0 + wm + mt*16 + li;
    int b = mm>>11, t = mm&2047;
    #pragma unroll
    for (int nt=0;nt<4;nt++){
      int nb = n0 + wn + nt*16 + q*4;
      const float* bias = (nb<512) ? (bk+nb) : (bv+nb-512);
      unsigned char* dst = (nb<512) ? Kf8 : Vf8;
      int nn = nb & 511;
      int h = nn>>6, d0 = nn&63;
      unsigned int p = 0;
      p = __builtin_amdgcn_cvt_pk_fp8_f32(acc[mt][nt][0]+bias[0], acc[mt][nt][1]+bias[1], p, false);
      p = __builtin_amdgcn_cvt_pk_fp8_f32(acc[mt][nt][2]+bias[2], acc[mt][nt][3]+bias[3], p, true);
      *(unsigned int*)&dst[(((size_t)(b*8+h))*T_ + (size_t)t)*64 + d0] = p;
    }
  }
}

// ---------------------------------------------------------------- attn_step
// One block (1024 thr, 16 waves) per (b,h). Each wave: 128 t-rows in 8 passes
// of 16 rows; lane = (ro=lane>>2, dq=lane&3) covering 16 d via uint4.
// Register double-buffer keeps 2x16B loads in flight per wave at all times.
__global__ __launch_bounds__(1024) void attn_step(
    const unsigned char* __restrict__ Kf8, const unsigned char* __restrict__ Vf8,
    const bf16* __restrict__ WqB, const bf16* __restrict__ WoT,
    const float* __restrict__ bq, const float* __restrict__ prefb,
    const float* __restrict__ h_prev, float* __restrict__ ctx_part)
{
  __shared__ float q_s[512];
  __shared__ float qh_s[64];
  __shared__ float aw[16][64];
  __shared__ float zw[16];
  __shared__ float attn_s[64];
  const int tid = threadIdx.x;
  const int b = blockIdx.x>>3, h = blockIdx.x&7;
  const int lane = tid&63, wave = tid>>6;
  if (tid < 512) q_s[tid] = (tid<256) ? h_prev[b*256+tid] : prefb[b*256+(tid-256)];
  __syncthreads();
  { // qh partials: wave w covers k=[w*32,w*32+32), lane = d. broadcast + coalesced.
    float sd = 0.f;
    const bf16* wq = &WqB[(size_t)(wave*32)*512 + h*64 + lane];
    #pragma unroll 8
    for (int i=0;i<32;i++) sd += q_s[wave*32+i]*(float)wq[(size_t)i*512];
    aw[wave][lane] = sd;
  }
  __syncthreads();
  if (tid < 64){
    float sd = 0.f;
    #pragma unroll
    for (int w=0;w<16;w++) sd += aw[w][tid];
    qh_s[tid] = (sd + bq[h*64+tid])*0.125f;
  }
  __syncthreads();
  const int ro = lane>>2, dq = lane&3;
  f32x2 qh2[8];
  #pragma unroll
  for (int j=0;j<8;j++){ qh2[j].x = qh_s[dq*16+j*2]; qh2[j].y = qh_s[dq*16+j*2+1]; }
  const unsigned char* Kb = Kf8 + ((size_t)(b*8+h))*T_*64;
  const unsigned char* Vb = Vf8 + ((size_t)(b*8+h))*T_*64;
  const size_t base0 = ((size_t)(wave*128 + ro))*64 + dq*16;
  uint4 kreg[2], vreg[2];
  kreg[0] = *(const uint4*)&Kb[base0];
  vreg[0] = *(const uint4*)&Vb[base0];
  f32x2 acc2[8];
  #pragma unroll
  for (int j=0;j<8;j++) acc2[j] = (f32x2){0.f,0.f};
  float z = 0.f;
  #pragma unroll
  for (int p=0;p<8;p++){
    if (p<7){
      kreg[(p+1)&1] = *(const uint4*)&Kb[base0 + (size_t)(p+1)*1024];
      vreg[(p+1)&1] = *(const uint4*)&Vb[base0 + (size_t)(p+1)*1024];
    }
    uint4 k4 = kreg[p&1], v4 = vreg[p&1];
    f32x2 s2;
    s2  = qh2[0]*__builtin_amdgcn_cvt_pk_f32_fp8(k4.x,false);
    s2 += qh2[1]*__builtin_amdgcn_cvt_pk_f32_fp8(k4.x,true);
    s2 += qh2[2]*__builtin_amdgcn_cvt_pk_f32_fp8(k4.y,false);
    s2 += qh2[3]*__builtin_amdgcn_cvt_pk_f32_fp8(k4.y,true);
    s2 += qh2[4]*__builtin_amdgcn_cvt_pk_f32_fp8(k4.z,false);
    s2 += qh2[5]*__builtin_amdgcn_cvt_pk_f32_fp8(k4.z,true);
    s2 += qh2[6]*__builtin_amdgcn_cvt_pk_f32_fp8(k4.w,false);
    s2 += qh2[7]*__builtin_amdgcn_cvt_pk_f32_fp8(k4.w,true);
    float sc = s2.x + s2.y;
    sc += __shfl_xor(sc,1); sc += __shfl_xor(sc,2);
    float e = __expf(fminf(sc, 80.f));
    z += e;
    f32x2 e2 = (f32x2){e,e};
    acc2[0] += e2*__builtin_amdgcn_cvt_pk_f32_fp8(v4.x,false);
    acc2[1] += e2*__builtin_amdgcn_cvt_pk_f32_fp8(v4.x,true);
    acc2[2] += e2*__builtin_amdgcn_cvt_pk_f32_fp8(v4.y,false);
    acc2[3] += e2*__builtin_amdgcn_cvt_pk_f32_fp8(v4.y,true);
    acc2[4] += e2*__builtin_amdgcn_cvt_pk_f32_fp8(v4.z,false);
    acc2[5] += e2*__builtin_amdgcn_cvt_pk_f32_fp8(v4.z,true);
    acc2[6] += e2*__builtin_amdgcn_cvt_pk_f32_fp8(v4.w,false);
    acc2[7] += e2*__builtin_amdgcn_cvt_pk_f32_fp8(v4.w,true);
  }
  // reduce over rows (ro bits: 4,8,16,32), dq preserved
  #pragma unroll
  for (int j=0;j<8;j++){
    acc2[j].x += __shfl_xor(acc2[j].x,4);  acc2[j].y += __shfl_xor(acc2[j].y,4);
    acc2[j].x += __shfl_xor(acc2[j].x,8);  acc2[j].y += __shfl_xor(acc2[j].y,8);
    acc2[j].x += __shfl_xor(acc2[j].x,16); acc2[j].y += __shfl_xor(acc2[j].y,16);
    acc2[j].x += __shfl_xor(acc2[j].x,32); acc2[j].y += __shfl_xor(acc2[j].y,32);
  }
  z += __shfl_xor(z,4); z += __shfl_xor(z,8); z += __shfl_xor(z,16); z += __shfl_xor(z,32);
  if (ro==0){
    #pragma unroll
    for (int j=0;j<8;j++){ aw[wave][dq*16+j*2] = acc2[j].x; aw[wave][dq*16+j*2+1] = acc2[j].y; }
    if (dq==0) zw[wave] = z;
  }
  __syncthreads();
  if (tid < 64){
    float Z = 0.f, a = 0.f;
    #pragma unroll
    for (int w=0;w<16;w++){ Z += zw[w]; a += aw[w][tid]; }
    attn_s[tid] = a / Z;
  }
  __syncthreads();
  { // ctx_part[(b,h), j] = attn . Wo[h*64:(h+1)*64, j]
    int j = tid>>2, p4 = tid&3;
    const bf16* wo = &WoT[(((size_t)h*256)+j)*64 + p4*16];
    const float* at = &attn_s[p4*16];
    float cp = 0.f;
    #pragma unroll
    for (int i=0;i<2;i++){
      bf16x8 w8 = *(const bf16x8*)&wo[i*8];
      #pragma unroll
      for (int u=0;u<8;u++) cp += at[i*8+u]*(float)w8[u];
    }
    cp += __shfl_xor(cp,1); cp += __shfl_xor(cp,2);
    if (p4==0) ctx_part[(size_t)(b*8+h)*256 + j] = cp;
  }
}

// ---------------------------------------------------------------- gates_step
// 256 blocks = (b, sub); block owns j = sub*32..+32 for all 4 gates (128 rows).
// 8-way k-split per row, bf16 weights (L2-resident per XCD), fused LSTM.
__global__ __launch_bounds__(1024) void gates_step(
    const float* __restrict__ h_prev, const float* __restrict__ ctx_part,
    const float* __restrict__ prefb, const float* __restrict__ bo,
    const bf16* __restrict__ WihB, const bf16* __restrict__ WhhB,
    const float* __restrict__ b_ih, const float* __restrict__ b_hh,
    float* __restrict__ c_cur, float* __restrict__ h_next,
    float* __restrict__ ctx_hist_s)
{
  __shared__ float xh_s[8*132];
  __shared__ float gv_s[128];
  const int tid = threadIdx.x;
  const int b = blockIdx.x>>3, sub = blockIdx.x&7;
  { int k = tid; float xv;
    if (k < 256) xv = h_prev[b*256+k];
    else if (k < 512){
      int j2 = k-256;
      float c8 = bo[j2];
      #pragma unroll
      for (int h2=0;h2<8;h2++) c8 += ctx_part[(size_t)(b*8+h2)*256 + j2];
      xv = c8;
      if (sub==0) ctx_hist_s[b*256+j2] = c8;
    }
    else if (k < 768) xv = prefb[b*256+(k-512)];
    else xv = h_prev[b*256+(k-768)];
    xh_s[(k>>7)*132 + (k&127)] = xv;     // padded: stride 132 per 128-chunk
  }
  __syncthreads();
  { int n4 = tid>>3, p = tid&7;
    int g = n4>>5, j = sub*32 + (n4&31);
    int n = g*256 + j;
    const bf16* w; const float* x;
    if (p < 6){ w = &WihB[(size_t)n*768 + p*128]; x = &xh_s[p*132]; }
    else      { w = &WhhB[(size_t)n*256 + (p-6)*128]; x = &xh_s[p*132]; }
    float sum = 0.f;
    #pragma unroll
    for (int i=0;i<16;i++){
      bf16x8 w8 = *(const bf16x8*)&w[i*8];
      const float* xx = &x[i*8];
      #pragma unroll
      for (int u=0;u<8;u++) sum += (float)w8[u]*xx[u];
    }
    sum += __shfl_xor(sum,1); sum += __shfl_xor(sum,2); sum += __shfl_xor(sum,4);
    if (p==0) gv_s[n4] = sum + b_ih[n] + b_hh[n];
  }
  __syncthreads();
  if (tid < 32){
    int j = sub*32 + tid;
    float iv = gv_s[tid], fv = gv_s[32+tid], gg = gv_s[64+tid], ov = gv_s[96+tid];
    float cp = c_cur[b*256+j];
    float cn = sigmoidf_(fv)*cp + sigmoidf_(iv)*tanhf_(gg);
    float hn = sigmoidf_(ov)*tanhf_(cn);
    c_cur[b*256+j] = cn;
    h_next[b*256+j] = hn;
  }
}

// ---------------------------------------------------------------- epilogue
__global__ __launch_bounds__(256) void epilogue_k(const float* __restrict__ h_hist, const float* __restrict__ ctx_hist,
                                                  const float* __restrict__ prefb, const float* __restrict__ hW1,
                                                  const float* __restrict__ hb1, const float* __restrict__ hW2,
                                                  const float* __restrict__ hb2, float* __restrict__ out)
{
  __shared__ float dec[8][768];
  __shared__ float hid[8][260];
  int blk = blockIdx.x;
  int tid = threadIdx.x;
  #pragma unroll
  for (int i=0;i<8;i++){
    int sb = blk*8+i;
    int s = sb>>5, b = sb&31;
    for (int k=tid; k<768; k+=256){
      float v;
      if (k<256)      v = h_hist[((size_t)(s+1)*32 + b)*256 + k];
      else if (k<512) v = ctx_hist[((size_t)s*32 + b)*256 + (k-256)];
      else            v = prefb[b*256 + (k-512)];
      dec[i][k] = v;
    }
  }
  __syncthreads();
  float a[8];
  #pragma unroll
  for (int i=0;i<8;i++) a[i]=0.f;
  for (int k=0;k<768;k++){
    float w = hW1[(size_t)k*256 + tid];
    #pragma unroll
    for (int i=0;i<8;i++) a[i] += dec[i][k]*w;
  }
  float b1 = hb1[tid];
  #pragma unroll
  for (int i=0;i<8;i++) hid[i][tid] = fmaxf(a[i]+b1, 0.f);
  __syncthreads();
  if (tid < 128){
    int i = tid>>4, r = tid&15;
    float s2 = 0.f;
    for (int j2=0;j2<256;j2++) s2 += hid[i][j2]*hW2[j2*16+r];
    s2 += hb2[r];
    int sb = blk*8+i;
    int st = sb>>5, b = sb&31;
    out[(size_t)b*512 + st*16 + r] = s2;
  }
}

// ---------------------------------------------------------------- launch
extern "C" void kernel_launch(void* const* d_in, const int* in_sizes, int n_in,
                              void* d_out, int out_size, void* d_ws, size_t ws_size,
                              hipStream_t stream)
{
  const float* X          = (const float*)d_in[0];
  const float* context    = (const float*)d_in[1];
  const float* preference = (const float*)d_in[2];
  const float* pref_W     = (const float*)d_in[3];
  const float* pref_b     = (const float*)d_in[4];
  const float* ln_g       = (const float*)d_in[5];
  const float* ln_b       = (const float*)d_in[6];
  const float* Wq         = (const float*)d_in[7];
  const float* bq         = (const float*)d_in[8];
  const float* Wk         = (const float*)d_in[9];
  const float* bk         = (const float*)d_in[10];
  const float* Wv         = (const float*)d_in[11];
  const float* bv         = (const float*)d_in[12];
  const float* Wo         = (const float*)d_in[13];
  const float* bo         = (const float*)d_in[14];
  const float* W_ih       = (const float*)d_in[15];
  const float* b_ih       = (const float*)d_in[16];
  const float* W_hh       = (const float*)d_in[17];
  const float* b_hh       = (const float*)d_in[18];
  const float* hW1        = (const float*)d_in[19];
  const float* hb1        = (const float*)d_in[20];
  const float* hW2        = (const float*)d_in[21];
  const float* hb2        = (const float*)d_in[22];
  float* out = (float*)d_out;

  char* ws = (char*)d_ws;
  size_t off = 0;
  auto alloc = [&](size_t bytes)->char*{ char* p = ws+off; off += (bytes+255)&~(size_t)255; return p; };
  bf16* Xb           = (bf16*)alloc((size_t)B_*T_*512*2);            // 67 MB
  unsigned char* Kf8 = (unsigned char*)alloc((size_t)B_*8*T_*64);    // 33.5 MB
  unsigned char* Vf8 = (unsigned char*)alloc((size_t)B_*8*T_*64);    // 33.5 MB
  bf16* WkvT     = (bf16*)alloc(1024ull*512*2);
  bf16* WqB      = (bf16*)alloc(512ull*512*2);
  bf16* WoT      = (bf16*)alloc(8ull*256*64*2);
  bf16* WihB     = (bf16*)alloc(1024ull*768*2);
  bf16* WhhB     = (bf16*)alloc(1024ull*256*2);
  float* prefb   = (float*)alloc(8192ull*4);
  float* h_hist  = (float*)alloc(33ull*8192*4);
  float* c_cur   = (float*)alloc(8192ull*4);
  float* ctx_part= (float*)alloc(256ull*256*4);
  float* ctx_hist= (float*)alloc(32ull*8192*4);
  (void)ws_size; (void)in_sizes; (void)n_in; (void)out_size;

  hipLaunchKernelGGL(prep_misc, dim3(2048), dim3(256), 0, stream,
                     X, Wq,Wk,Wv,Wo,W_ih,W_hh, context,
                     Xb, WkvT,WqB,WoT,WihB,WhhB, h_hist, c_cur);
  hipLaunchKernelGGL(prep_pref, dim3(32), dim3(256), 0, stream,
                     preference, pref_W, pref_b, ln_g, ln_b, prefb);
  hipLaunchKernelGGL(gemm_kv, dim3(4096), dim3(256), 0, stream, Xb, WkvT, bk, bv, Kf8, Vf8);
  for (int s=0;s<S_;s++){
    hipLaunchKernelGGL(attn_step, dim3(256), dim3(1024), 0, stream,
                       Kf8, Vf8, WqB, WoT, bq, prefb,
                       h_hist + (size_t)s*8192, ctx_part);
    hipLaunchKernelGGL(gates_step, dim3(256), dim3(1024), 0, stream,
                       h_hist + (size_t)s*8192, ctx_part, prefb, bo,
                       WihB, WhhB, b_ih, b_hh,
                       c_cur, h_hist + (size_t)(s+1)*8192,
                       ctx_hist + (size_t)s*8192);
  }
  hipLaunchKernelGGL(epilogue_k, dim3(128), dim3(256), 0, stream,
                     h_hist, ctx_hist, prefb, hW1, hb1, hW2, hb2, out);
}